// Round 4
// baseline (216.196 us; speedup 1.0000x reference)
//
#include <hip/hip_runtime.h>

#define N_NODES 50000
#define N_EDGES 800000
#define H 64
#define NBLK 196   // ceil(50000/256)
#define NPW 8      // nodes per wave in fused kernel

__device__ __forceinline__ float readlane_f(float x, int i) {
    return __int_as_float(__builtin_amdgcn_readlane(__float_as_int(x), i));
}

// ---- Stage 1: histogram of receiver counts (4 edges/thread, int4 loads) ----
__global__ __launch_bounds__(256) void hist_kernel(
    const int* __restrict__ recv, unsigned* __restrict__ counts)
{
    int i = blockIdx.x * 256 + threadIdx.x;
    if (i < N_EDGES / 4) {
        int4 r = reinterpret_cast<const int4*>(recv)[i];
        atomicAdd(&counts[r.x], 1u);
        atomicAdd(&counts[r.y], 1u);
        atomicAdd(&counts[r.z], 1u);
        atomicAdd(&counts[r.w], 1u);
    }
}

// ---- Stage 2a: per-block reduce of counts ----
__global__ __launch_bounds__(256) void scanA_kernel(
    const unsigned* __restrict__ counts, unsigned* __restrict__ blockSums)
{
    __shared__ unsigned red[256];
    int i = blockIdx.x * 256 + threadIdx.x;
    unsigned s = (i < N_NODES) ? counts[i] : 0u;
    red[threadIdx.x] = s;
    __syncthreads();
    for (int off = 128; off > 0; off >>= 1) {
        if (threadIdx.x < off) red[threadIdx.x] += red[threadIdx.x + off];
        __syncthreads();
    }
    if (threadIdx.x == 0) blockSums[blockIdx.x] = red[0];
}

// ---- Stage 2b: exclusive scan of the 196 block sums (1 block) ----
__global__ __launch_bounds__(256) void scanB_kernel(
    const unsigned* __restrict__ blockSums, unsigned* __restrict__ blockPrefix)
{
    __shared__ unsigned sh[256];
    int t = threadIdx.x;
    unsigned s = (t < NBLK) ? blockSums[t] : 0u;
    sh[t] = s;
    __syncthreads();
    for (int off = 1; off < 256; off <<= 1) {
        unsigned vv = (t >= off) ? sh[t - off] : 0u;
        __syncthreads();
        sh[t] += vv;
        __syncthreads();
    }
    if (t < NBLK) blockPrefix[t] = sh[t] - s;   // exclusive
}

// ---- Stage 2c: per-block exclusive scan + add block prefix ----
__global__ __launch_bounds__(256) void scanC_kernel(
    const unsigned* __restrict__ counts, const unsigned* __restrict__ blockPrefix,
    unsigned* __restrict__ offsets, unsigned* __restrict__ cursor)
{
    __shared__ unsigned sh[256];
    int t = threadIdx.x;
    int i = blockIdx.x * 256 + t;
    unsigned c = (i < N_NODES) ? counts[i] : 0u;
    sh[t] = c;
    __syncthreads();
    for (int off = 1; off < 256; off <<= 1) {
        unsigned vv = (t >= off) ? sh[t - off] : 0u;
        __syncthreads();
        sh[t] += vv;
        __syncthreads();
    }
    unsigned ex = sh[t] - c + blockPrefix[blockIdx.x];
    if (i < N_NODES) { offsets[i] = ex; cursor[i] = ex; }
    if (i == 0) offsets[N_NODES] = N_EDGES;
}

// ---- Stage 3: scatter edge ids into receiver buckets ----
__global__ __launch_bounds__(256) void bucket_kernel(
    const int* __restrict__ recv, unsigned* __restrict__ cursor,
    unsigned* __restrict__ perm)
{
    int i = blockIdx.x * 256 + threadIdx.x;
    if (i < N_EDGES / 4) {
        int4 r = reinterpret_cast<const int4*>(recv)[i];
        unsigned p0 = atomicAdd(&cursor[r.x], 1u);
        unsigned p1 = atomicAdd(&cursor[r.y], 1u);
        unsigned p2 = atomicAdd(&cursor[r.z], 1u);
        unsigned p3 = atomicAdd(&cursor[r.w], 1u);
        perm[p0] = (unsigned)(i * 4 + 0);
        perm[p1] = (unsigned)(i * 4 + 1);
        perm[p2] = (unsigned)(i * 4 + 2);
        perm[p3] = (unsigned)(i * 4 + 3);
    }
}

// ---- Stage 4: fused gather-mean + 3-layer MLP ----
// 1024 threads = 16 waves; 8 nodes per wave; lane j = feature j.
// One ds_read_b32 weight read is amortized over 8 nodes (8 readlane+fmac).
__global__ __launch_bounds__(1024, 2) void gather_mlp_kernel(
    const float* __restrict__ E, const unsigned* __restrict__ offsets,
    const unsigned* __restrict__ perm, const float* __restrict__ v,
    const float* __restrict__ W0, const float* __restrict__ b0,
    const float* __restrict__ W1, const float* __restrict__ b1,
    const float* __restrict__ W2, const float* __restrict__ b2,
    float* __restrict__ out)
{
    __shared__ float sW0[128 * 64];
    __shared__ float sW1[64 * 64];
    __shared__ float sW2[64 * 64];
    __shared__ float sB[3 * 64];

    for (int i = threadIdx.x; i < 128 * 64; i += 1024) sW0[i] = W0[i];
    for (int i = threadIdx.x; i < 64 * 64; i += 1024) sW1[i] = W1[i];
    for (int i = threadIdx.x; i < 64 * 64; i += 1024) sW2[i] = W2[i];
    if (threadIdx.x < 192) {
        sB[threadIdx.x] = (threadIdx.x < 64)   ? b0[threadIdx.x]
                        : (threadIdx.x < 128)  ? b1[threadIdx.x - 64]
                                               : b2[threadIdx.x - 128];
    }
    __syncthreads();

    const int lane = threadIdx.x & 63;
    int nodeBase = blockIdx.x * (16 * NPW) + (threadIdx.x >> 6) * NPW;
    nodeBase = __builtin_amdgcn_readfirstlane(nodeBase);
    if (nodeBase >= N_NODES) return;   // whole-wave tail exit (after syncthreads)

    // ---- gather mean for NPW nodes (only xa[] live in this phase) ----
    float xa[NPW];
    #pragma unroll
    for (int k = 0; k < NPW; ++k) {
        int n = nodeBase + k;
        float a0 = 0.f, a1 = 0.f, a2 = 0.f, a3 = 0.f;
        int cnt = 0;
        if (n < N_NODES) {
            int beg = __builtin_amdgcn_readfirstlane((int)offsets[n]);
            int end = __builtin_amdgcn_readfirstlane((int)offsets[n + 1]);
            cnt = end - beg;
            int p = beg;
            for (; p + 3 < end; p += 4) {
                int e0 = (int)perm[p];
                int e1 = (int)perm[p + 1];
                int e2 = (int)perm[p + 2];
                int e3 = (int)perm[p + 3];
                a0 += E[(size_t)e0 * H + lane];
                a1 += E[(size_t)e1 * H + lane];
                a2 += E[(size_t)e2 * H + lane];
                a3 += E[(size_t)e3 * H + lane];
            }
            for (; p < end; ++p) a0 += E[(size_t)perm[p] * H + lane];
        }
        float invc = (cnt > 0) ? 1.0f / (float)cnt : 0.0f;
        xa[k] = (a0 + a1 + a2 + a3) * invc;
    }

    // ---- v rows (coalesced) ----
    float xv[NPW];
    #pragma unroll
    for (int k = 0; k < NPW; ++k) {
        int n = nodeBase + k;
        xv[k] = (n < N_NODES) ? v[(size_t)n * H + lane] : 0.0f;
    }

    // ---- MLP: 1 LDS weight read per K-step, shared by NPW nodes ----
    float acc[NPW];
    #pragma unroll
    for (int k = 0; k < NPW; ++k) acc[k] = sB[lane];
    #pragma unroll 8
    for (int i = 0; i < 64; ++i) {
        float w = sW0[i * 64 + lane];
        #pragma unroll
        for (int k = 0; k < NPW; ++k) acc[k] = fmaf(readlane_f(xa[k], i), w, acc[k]);
    }
    #pragma unroll 8
    for (int i = 0; i < 64; ++i) {
        float w = sW0[(64 + i) * 64 + lane];
        #pragma unroll
        for (int k = 0; k < NPW; ++k) acc[k] = fmaf(readlane_f(xv[k], i), w, acc[k]);
    }
    float y[NPW];
    #pragma unroll
    for (int k = 0; k < NPW; ++k) y[k] = fmaxf(acc[k], 0.0f);

    #pragma unroll
    for (int k = 0; k < NPW; ++k) acc[k] = sB[64 + lane];
    #pragma unroll 8
    for (int i = 0; i < 64; ++i) {
        float w = sW1[i * 64 + lane];
        #pragma unroll
        for (int k = 0; k < NPW; ++k) acc[k] = fmaf(readlane_f(y[k], i), w, acc[k]);
    }
    float z[NPW];
    #pragma unroll
    for (int k = 0; k < NPW; ++k) z[k] = fmaxf(acc[k], 0.0f);

    #pragma unroll
    for (int k = 0; k < NPW; ++k) acc[k] = sB[128 + lane];
    #pragma unroll 8
    for (int i = 0; i < 64; ++i) {
        float w = sW2[i * 64 + lane];
        #pragma unroll
        for (int k = 0; k < NPW; ++k) acc[k] = fmaf(readlane_f(z[k], i), w, acc[k]);
    }

    #pragma unroll
    for (int k = 0; k < NPW; ++k) {
        int n = nodeBase + k;
        if (n < N_NODES) out[(size_t)n * H + lane] = acc[k];
    }
}

extern "C" void kernel_launch(void* const* d_in, const int* in_sizes, int n_in,
                              void* d_out, int out_size, void* d_ws, size_t ws_size,
                              hipStream_t stream)
{
    const float* v  = (const float*)d_in[0];
    const int*   ei = (const int*)d_in[1];     // [2, 800000]; row 1 = receiver
    const float* e  = (const float*)d_in[2];
    const float* W0 = (const float*)d_in[3];
    const float* b0 = (const float*)d_in[4];
    const float* W1 = (const float*)d_in[5];
    const float* b1 = (const float*)d_in[6];
    const float* W2 = (const float*)d_in[7];
    const float* b2 = (const float*)d_in[8];
    float* out = (float*)d_out;

    // workspace layout (u32 elements)
    unsigned* W = (unsigned*)d_ws;
    unsigned* counts      = W;                  // [0, 50176)
    unsigned* offsets     = W + 50176;          // 50001 (+pad)
    unsigned* cursor      = W + 100224;         // 50000 (+pad)
    unsigned* blockSums   = W + 150272;         // 196 (+pad)
    unsigned* blockPrefix = W + 150528;         // 196 (+pad)
    unsigned* perm        = W + 150784;         // 800000
    const int* recv = ei + N_EDGES;

    hipMemsetAsync(counts, 0, N_NODES * sizeof(unsigned), stream);

    hist_kernel<<<(N_EDGES / 4 + 255) / 256, 256, 0, stream>>>(recv, counts);
    scanA_kernel<<<NBLK, 256, 0, stream>>>(counts, blockSums);
    scanB_kernel<<<1, 256, 0, stream>>>(blockSums, blockPrefix);
    scanC_kernel<<<NBLK, 256, 0, stream>>>(counts, blockPrefix, offsets, cursor);
    bucket_kernel<<<(N_EDGES / 4 + 255) / 256, 256, 0, stream>>>(recv, cursor, perm);

    const int nodesPerBlock = 16 * NPW;  // 128
    gather_mlp_kernel<<<(N_NODES + nodesPerBlock - 1) / nodesPerBlock, 1024, 0, stream>>>(
        e, offsets, perm, v, W0, b0, W1, b1, W2, b2, out);
}

// Round 5
// 199.850 us; speedup vs baseline: 1.0818x; 1.0818x over previous
//
#include <hip/hip_runtime.h>

#define N_NODES 50000
#define N_EDGES 800000
#define H 64
#define NBLK 196        // ceil(50000/256)
#define TOTAL_WAVES 8192
#define NPWMAX 7        // ceil(50000/8192)

__device__ __forceinline__ float readlane_f(float x, int i) {
    return __int_as_float(__builtin_amdgcn_readlane(__float_as_int(x), i));
}

// ---- Stage 1: histogram of receiver counts (4 edges/thread, int4 loads) ----
__global__ __launch_bounds__(256) void hist_kernel(
    const int* __restrict__ recv, unsigned* __restrict__ counts)
{
    int i = blockIdx.x * 256 + threadIdx.x;
    if (i < N_EDGES / 4) {
        int4 r = reinterpret_cast<const int4*>(recv)[i];
        atomicAdd(&counts[r.x], 1u);
        atomicAdd(&counts[r.y], 1u);
        atomicAdd(&counts[r.z], 1u);
        atomicAdd(&counts[r.w], 1u);
    }
}

// ---- Stage 2a: per-block reduce of counts ----
__global__ __launch_bounds__(256) void scanA_kernel(
    const unsigned* __restrict__ counts, unsigned* __restrict__ blockSums)
{
    __shared__ unsigned red[256];
    int i = blockIdx.x * 256 + threadIdx.x;
    unsigned s = (i < N_NODES) ? counts[i] : 0u;
    red[threadIdx.x] = s;
    __syncthreads();
    for (int off = 128; off > 0; off >>= 1) {
        if (threadIdx.x < off) red[threadIdx.x] += red[threadIdx.x + off];
        __syncthreads();
    }
    if (threadIdx.x == 0) blockSums[blockIdx.x] = red[0];
}

// ---- Stage 2b: per-block scan; each block derives its own prefix from blockSums ----
__global__ __launch_bounds__(256) void scanC_kernel(
    const unsigned* __restrict__ counts, const unsigned* __restrict__ blockSums,
    unsigned* __restrict__ offsets, unsigned* __restrict__ cursor)
{
    __shared__ unsigned sh[256];
    const int t = threadIdx.x;

    // block prefix = sum of blockSums[0..blockIdx.x)
    sh[t] = (t < blockIdx.x && t < NBLK) ? blockSums[t] : 0u;
    __syncthreads();
    for (int off = 128; off > 0; off >>= 1) {
        if (t < off) sh[t] += sh[t + off];
        __syncthreads();
    }
    unsigned blockPrefix = sh[0];
    __syncthreads();

    // local exclusive scan of this block's 256 counts
    int i = blockIdx.x * 256 + t;
    unsigned c = (i < N_NODES) ? counts[i] : 0u;
    sh[t] = c;
    __syncthreads();
    for (int off = 1; off < 256; off <<= 1) {
        unsigned vv = (t >= off) ? sh[t - off] : 0u;
        __syncthreads();
        sh[t] += vv;
        __syncthreads();
    }
    unsigned ex = sh[t] - c + blockPrefix;
    if (i < N_NODES) { offsets[i] = ex; cursor[i] = ex; }
    if (i == 0) offsets[N_NODES] = N_EDGES;
}

// ---- Stage 3: scatter edge ids into receiver buckets ----
__global__ __launch_bounds__(256) void bucket_kernel(
    const int* __restrict__ recv, unsigned* __restrict__ cursor,
    unsigned* __restrict__ perm)
{
    int i = blockIdx.x * 256 + threadIdx.x;
    if (i < N_EDGES / 4) {
        int4 r = reinterpret_cast<const int4*>(recv)[i];
        unsigned p0 = atomicAdd(&cursor[r.x], 1u);
        unsigned p1 = atomicAdd(&cursor[r.y], 1u);
        unsigned p2 = atomicAdd(&cursor[r.z], 1u);
        unsigned p3 = atomicAdd(&cursor[r.w], 1u);
        perm[p0] = (unsigned)(i * 4 + 0);
        perm[p1] = (unsigned)(i * 4 + 1);
        perm[p2] = (unsigned)(i * 4 + 2);
        perm[p3] = (unsigned)(i * 4 + 3);
    }
}

// ---- Stage 4: fused gather-mean + 3-layer MLP ----
// Exactly 512 blocks x 1024 threads = 8192 waves (2 blocks/CU resident by LDS).
// Wave g handles nodes {g + j*8192 : j=0..6} -> 6-7 nodes/wave, perfectly balanced.
// One ds_read_b32 weight read amortized over ~6.5 nodes; lane j = feature j.
__global__ __launch_bounds__(1024, 8) void gather_mlp_kernel(
    const float* __restrict__ E, const unsigned* __restrict__ offsets,
    const unsigned* __restrict__ perm, const float* __restrict__ v,
    const float* __restrict__ W0, const float* __restrict__ b0,
    const float* __restrict__ W1, const float* __restrict__ b1,
    const float* __restrict__ W2, const float* __restrict__ b2,
    float* __restrict__ out)
{
    __shared__ float sW0[128 * 64];
    __shared__ float sW1[64 * 64];
    __shared__ float sW2[64 * 64];
    __shared__ float sB[3 * 64];

    for (int i = threadIdx.x; i < 128 * 64; i += 1024) sW0[i] = W0[i];
    for (int i = threadIdx.x; i < 64 * 64; i += 1024) sW1[i] = W1[i];
    for (int i = threadIdx.x; i < 64 * 64; i += 1024) sW2[i] = W2[i];
    if (threadIdx.x < 192) {
        sB[threadIdx.x] = (threadIdx.x < 64)   ? b0[threadIdx.x]
                        : (threadIdx.x < 128)  ? b1[threadIdx.x - 64]
                                               : b2[threadIdx.x - 128];
    }
    __syncthreads();

    const int lane = threadIdx.x & 63;
    int g = (blockIdx.x * 1024 + threadIdx.x) >> 6;
    g = __builtin_amdgcn_readfirstlane(g);

    // ---- gather mean + v row for up to 7 strided nodes ----
    float xa[NPWMAX], xv[NPWMAX];
    #pragma unroll
    for (int j = 0; j < NPWMAX; ++j) {
        int n = g + j * TOTAL_WAVES;
        xa[j] = 0.0f;
        xv[j] = 0.0f;
        if (n < N_NODES) {
            xv[j] = v[(size_t)n * H + lane];
            int beg = __builtin_amdgcn_readfirstlane((int)offsets[n]);
            int end = __builtin_amdgcn_readfirstlane((int)offsets[n + 1]);
            int cnt = end - beg;
            float a0 = 0.f, a1 = 0.f, a2 = 0.f, a3 = 0.f;
            int p = beg;
            for (; p + 3 < end; p += 4) {
                int e0 = (int)perm[p];
                int e1 = (int)perm[p + 1];
                int e2 = (int)perm[p + 2];
                int e3 = (int)perm[p + 3];
                a0 += E[(size_t)e0 * H + lane];
                a1 += E[(size_t)e1 * H + lane];
                a2 += E[(size_t)e2 * H + lane];
                a3 += E[(size_t)e3 * H + lane];
            }
            for (; p < end; ++p) a0 += E[(size_t)perm[p] * H + lane];
            float invc = (cnt > 0) ? 1.0f / (float)cnt : 0.0f;
            xa[j] = (a0 + a1 + a2 + a3) * invc;
        }
    }

    // ---- MLP: 1 LDS weight read per K-step, shared by ~6.5 nodes ----
    float acc[NPWMAX];
    #pragma unroll
    for (int j = 0; j < NPWMAX; ++j) acc[j] = sB[lane];
    #pragma unroll 8
    for (int i = 0; i < 64; ++i) {
        float w = sW0[i * 64 + lane];
        #pragma unroll
        for (int j = 0; j < NPWMAX; ++j) acc[j] = fmaf(readlane_f(xa[j], i), w, acc[j]);
    }
    #pragma unroll 8
    for (int i = 0; i < 64; ++i) {
        float w = sW0[(64 + i) * 64 + lane];
        #pragma unroll
        for (int j = 0; j < NPWMAX; ++j) acc[j] = fmaf(readlane_f(xv[j], i), w, acc[j]);
    }
    float y[NPWMAX];
    #pragma unroll
    for (int j = 0; j < NPWMAX; ++j) y[j] = fmaxf(acc[j], 0.0f);

    #pragma unroll
    for (int j = 0; j < NPWMAX; ++j) acc[j] = sB[64 + lane];
    #pragma unroll 8
    for (int i = 0; i < 64; ++i) {
        float w = sW1[i * 64 + lane];
        #pragma unroll
        for (int j = 0; j < NPWMAX; ++j) acc[j] = fmaf(readlane_f(y[j], i), w, acc[j]);
    }
    float z[NPWMAX];
    #pragma unroll
    for (int j = 0; j < NPWMAX; ++j) z[j] = fmaxf(acc[j], 0.0f);

    #pragma unroll
    for (int j = 0; j < NPWMAX; ++j) acc[j] = sB[128 + lane];
    #pragma unroll 8
    for (int i = 0; i < 64; ++i) {
        float w = sW2[i * 64 + lane];
        #pragma unroll
        for (int j = 0; j < NPWMAX; ++j) acc[j] = fmaf(readlane_f(z[j], i), w, acc[j]);
    }

    #pragma unroll
    for (int j = 0; j < NPWMAX; ++j) {
        int n = g + j * TOTAL_WAVES;
        if (n < N_NODES) out[(size_t)n * H + lane] = acc[j];
    }
}

extern "C" void kernel_launch(void* const* d_in, const int* in_sizes, int n_in,
                              void* d_out, int out_size, void* d_ws, size_t ws_size,
                              hipStream_t stream)
{
    const float* v  = (const float*)d_in[0];
    const int*   ei = (const int*)d_in[1];     // [2, 800000]; row 1 = receiver
    const float* e  = (const float*)d_in[2];
    const float* W0 = (const float*)d_in[3];
    const float* b0 = (const float*)d_in[4];
    const float* W1 = (const float*)d_in[5];
    const float* b1 = (const float*)d_in[6];
    const float* W2 = (const float*)d_in[7];
    const float* b2 = (const float*)d_in[8];
    float* out = (float*)d_out;

    // workspace layout (u32 elements)
    unsigned* W = (unsigned*)d_ws;
    unsigned* counts    = W;                  // [0, 50176)
    unsigned* offsets   = W + 50176;          // 50001 (+pad)
    unsigned* cursor    = W + 100224;         // 50000 (+pad)
    unsigned* blockSums = W + 150272;         // 196 (+pad)
    unsigned* perm      = W + 150784;         // 800000
    const int* recv = ei + N_EDGES;

    hipMemsetAsync(counts, 0, N_NODES * sizeof(unsigned), stream);

    hist_kernel<<<(N_EDGES / 4 + 255) / 256, 256, 0, stream>>>(recv, counts);
    scanA_kernel<<<NBLK, 256, 0, stream>>>(counts, blockSums);
    scanC_kernel<<<NBLK, 256, 0, stream>>>(counts, blockSums, offsets, cursor);
    bucket_kernel<<<(N_EDGES / 4 + 255) / 256, 256, 0, stream>>>(recv, cursor, perm);
    gather_mlp_kernel<<<512, 1024, 0, stream>>>(
        e, offsets, perm, v, W0, b0, W1, b1, W2, b2, out);
}